// Round 10
// baseline (70.469 us; speedup 1.0000x reference)
//
#include <hip/hip_runtime.h>
#include <math.h>

// out[b,c] = tanh( sum_{hw} x[b,c,h,w] * W[c,h,w] + bias[c] )
// x: [B=4096, C=512, 7, 7] f32; each (b,c) row = 49 contiguous floats.
//
// R10 = R9 (zero-barrier wave-private NT pipeline, 70.3 us) + DEPTH-2
// register prefetch (pA/pB ping-pong):
//   bodyA: write pA(t) -> LDS; issue NT loads t+2 -> pA; compute t
//   bodyB: write pB(t+1)-> LDS; issue NT loads t+3 -> pB; compute t+1
// Cover for each tile's loads = compute + entire other body (~1000 cy)
// > ~900 cy HBM latency (R9's depth-1 left ~500 cy exposed).
// Cost: ~+52 VGPR -> ~8 waves/CU (was 12); MLP replaces TLP.
// Static pA_/pB_ names (rule #20: no runtime-indexed register arrays).

constexpr int K    = 49;   // 7*7
constexpr int ROWS = 256;  // rows per block tile (64 per wave)
constexpr int GRID = 2048; // EVEN => channel c loop-invariant per block;
                           // n_tiles/GRID = 4 iterations (even => clean pairs)

typedef float f32x4 __attribute__((ext_vector_type(4)));

__global__ __launch_bounds__(256) void WGP_84018150245011_kernel(
    const float* __restrict__ x,
    const float* __restrict__ W,
    const float* __restrict__ bias,
    float* __restrict__ out,
    int n_tiles) {
  __shared__ float xs[ROWS * K];  // 50176 B; per-wave private quarters

  const int tid  = threadIdx.x;
  const int wave = tid >> 6;
  const int lane = tid & 63;

  // row = g*256 + tid, c = row % 512 = ((g&1)<<8)|tid; g&1 == blockIdx.x&1.
  const int c = ((blockIdx.x & 1) << 8) | tid;

  float w[K];
  const float* __restrict__ wr = W + c * K;
#pragma unroll
  for (int k = 0; k < K; ++k) w[k] = wr[k];
  const float bi = bias[c];

  // Wave-private LDS quarter: rows [64*wave, 64*wave+64).
  float* myq  = xs + wave * (64 * K);           // 3136 floats = 784 float4
  f32x4* dst4 = reinterpret_cast<f32x4*>(myq);
  const float* xr = myq + lane * K;             // stride 49 -> bank stride 17, conflict-free

  // Two prefetch register sets (depth-2). 784 float4 / 64 lanes = 12 + tail(16 lanes).
  f32x4 pA[12], pB[12];
  f32x4 tailA, tailB;

  auto issueA = [&](int g) {
    const f32x4* __restrict__ src4 =
        reinterpret_cast<const f32x4*>(x) + (size_t)g * (ROWS * K / 4) + wave * 784;
#pragma unroll
    for (int j = 0; j < 12; ++j) pA[j] = __builtin_nontemporal_load(&src4[lane + j * 64]);
    if (lane < 16) tailA = __builtin_nontemporal_load(&src4[768 + lane]);
  };
  auto issueB = [&](int g) {
    const f32x4* __restrict__ src4 =
        reinterpret_cast<const f32x4*>(x) + (size_t)g * (ROWS * K / 4) + wave * 784;
#pragma unroll
    for (int j = 0; j < 12; ++j) pB[j] = __builtin_nontemporal_load(&src4[lane + j * 64]);
    if (lane < 16) tailB = __builtin_nontemporal_load(&src4[768 + lane]);
  };

  auto compute = [&](int g) {
    float s = bi;
#pragma unroll
    for (int k = 0; k < K; ++k) s = fmaf(xr[k], w[k], s);
    __builtin_nontemporal_store(tanhf(s), &out[(size_t)g * ROWS + tid]);
  };

  const int iters = n_tiles / GRID;  // 4 (even)
  int g = blockIdx.x;

  // Prologue: two tiles in flight.
  issueA(g);
  issueB(g + GRID);

#pragma unroll 1
  for (int k = 0; k < iters; k += 2) {
    // ---- body A: tile g (register set pA) ----
#pragma unroll
    for (int j = 0; j < 12; ++j) dst4[lane + j * 64] = pA[j];  // vmcnt waits on pA
    if (lane < 16) dst4[768 + lane] = tailA;
    if (k + 2 < iters) issueA(g + 2 * GRID);
    compute(g);

    // ---- body B: tile g+GRID (register set pB) ----
#pragma unroll
    for (int j = 0; j < 12; ++j) dst4[lane + j * 64] = pB[j];  // vmcnt waits on pB
    if (lane < 16) dst4[768 + lane] = tailB;
    if (k + 3 < iters) issueB(g + 3 * GRID);
    compute(g + GRID);

    g += 2 * GRID;
  }
}

extern "C" void kernel_launch(void* const* d_in, const int* in_sizes, int n_in,
                              void* d_out, int out_size, void* d_ws, size_t ws_size,
                              hipStream_t stream) {
  const float* x    = (const float*)d_in[0];
  const float* W    = (const float*)d_in[1];
  const float* bias = (const float*)d_in[2];
  float* out        = (float*)d_out;

  const int n_rows  = in_sizes[0] / K;       // B*C = 2,097,152
  const int n_tiles = n_rows / ROWS;         // 8192; 8192/2048 = 4 iters (even)

  WGP_84018150245011_kernel<<<GRID, ROWS, 0, stream>>>(x, W, bias, out, n_tiles);
}